// Round 10
// baseline (219.805 us; speedup 1.0000x reference)
//
#include <hip/hip_runtime.h>
#include <hip/hip_bf16.h>

typedef __attribute__((ext_vector_type(8))) short short8;
typedef __attribute__((ext_vector_type(4))) float f32x4;

#define B_   16
#define O_   512
#define C_   512
#define T_   4096
#define TP   (T_ + 32)     // padded t extent: 16 zero rows each side
#define KT   5
#define OC   (O_ * C_)

__device__ __forceinline__ void gload_lds16(const void* g, void* l) {
    __builtin_amdgcn_global_load_lds(
        (const __attribute__((address_space(1))) unsigned int*)g,
        (__attribute__((address_space(3))) unsigned int*)l, 16, 0, 0);
}

// ---------------- fused prep: wrepack (blocks 0..5119) + padzero (5120..6143) ----
__global__ void prep_kernel(const float* __restrict__ w,
                            unsigned short* __restrict__ wb,
                            unsigned short* __restrict__ xt) {
    int bid = blockIdx.x;
    if (bid < 5120) {
        int e   = bid * 256 + threadIdx.x;
        int n   = e / OC;
        int rem = e % OC;
        int o   = rem / C_;
        int c   = rem % C_;
        float v = w[((size_t)o * C_ + c) * KT + n];
        __hip_bfloat16 h = __float2bfloat16(v);
        wb[e] = *reinterpret_cast<unsigned short*>(&h);
    } else {
        int i = (bid - 5120) * 256 + threadIdx.x;
        int b = i / (32 * C_);
        int r = (i / C_) % 32;
        int c = i % C_;
        int tp = (r < 16) ? r : (T_ + r);
        xt[((size_t)b * TP + tp) * C_ + c] = 0;
    }
}

// ---------------- x transpose: x[b][c][t] f32 -> xT[b][16+t][c] bf16 ----------------
__global__ void xtrans_kernel(const float* __restrict__ x, unsigned short* __restrict__ xt) {
    __shared__ float tile[64][65];
    int b  = blockIdx.z;
    int c0 = blockIdx.y * 64;
    int t0 = blockIdx.x * 64;
    const float* xb = x + ((size_t)b * C_ + c0) * T_ + t0;
#pragma unroll
    for (int p = 0; p < 4; ++p) {
        int idx = p * 256 + threadIdx.x;
        int cl = idx >> 4;
        int tj = (idx & 15) << 2;
        float4 v = *reinterpret_cast<const float4*>(xb + (size_t)cl * T_ + tj);
        tile[cl][tj + 0] = v.x;
        tile[cl][tj + 1] = v.y;
        tile[cl][tj + 2] = v.z;
        tile[cl][tj + 3] = v.w;
    }
    __syncthreads();
    unsigned short* xtb = xt + ((size_t)b * TP + 16 + t0) * C_ + c0;
#pragma unroll
    for (int p = 0; p < 2; ++p) {
        int g  = p * 256 + threadIdx.x;
        int tl = g >> 3;
        int cj = (g & 7) << 3;
        unsigned short tmp[8];
#pragma unroll
        for (int i = 0; i < 8; ++i) {
            __hip_bfloat16 h = __float2bfloat16(tile[cj + i][tl]);
            tmp[i] = *reinterpret_cast<unsigned short*>(&h);
        }
        *reinterpret_cast<short8*>(xtb + (size_t)tl * C_ + cj) =
            *reinterpret_cast<const short8*>(tmp);
    }
}

// ---------------- conv-as-GEMM, im2col K=2560, 8-phase-template schedule ----------
#define VM8 asm volatile("s_waitcnt vmcnt(8)" ::: "memory")
#define VM4 asm volatile("s_waitcnt vmcnt(4)" ::: "memory")
#define VM0 asm volatile("s_waitcnt vmcnt(0)" ::: "memory")
#define VMNONE

#define HALF_BODY(SLOT, HN, DO_ISSUE, VMW)                                          \
    {                                                                               \
        const unsigned short* alp = &a_lds[SLOT][0];                                \
        const unsigned short* blp = &b_lds[SLOT][0];                                \
        short8 af[8], bf[4];                                                        \
        _Pragma("unroll")                                                           \
        for (int mi = 0; mi < 4; ++mi)                                              \
            af[mi] = *reinterpret_cast<const short8*>(&alp[ao[mi]]);                \
        _Pragma("unroll")                                                           \
        for (int ni = 0; ni < 4; ++ni)                                              \
            bf[ni] = *reinterpret_cast<const short8*>(&blp[bo[ni]]);                \
        if (DO_ISSUE) {                                                             \
            int H3  = (HN) + 3;                                                     \
            int j3  = H3 >> 1;                                                      \
            int n3  = j3 >> 3;                                                      \
            size_t off3 = (size_t)(((j3 & 7) << 6) + ((H3 & 1) << 5));              \
            unsigned short* ad = &a_lds[((SLOT) + 3) & 3][wid * 1024];              \
            unsigned short* bd = &b_lds[((SLOT) + 3) & 3][wid * 1024];              \
            const unsigned short* as = agl + (size_t)n3 * OC + off3;                \
            const unsigned short* bs = bgl + (ptrdiff_t)(2 - n3) * C_ + off3;       \
            gload_lds16(as, ad);                                                    \
            gload_lds16(as + 16 * C_, ad + 512);                                    \
            gload_lds16(bs, bd);                                                    \
            gload_lds16(bs + 16 * C_, bd + 512);                                    \
        }                                                                           \
        __builtin_amdgcn_s_barrier();                                               \
        __builtin_amdgcn_s_setprio(1);                                              \
        _Pragma("unroll")                                                           \
        for (int mi = 0; mi < 4; ++mi)                                              \
            _Pragma("unroll")                                                       \
            for (int ni = 0; ni < 4; ++ni)                                          \
                acc[mi][ni] = __builtin_amdgcn_mfma_f32_16x16x32_bf16(              \
                    af[mi], bf[ni], acc[mi][ni], 0, 0, 0);                          \
        __builtin_amdgcn_s_setprio(0);                                              \
        __builtin_amdgcn_s_barrier();                                               \
        _Pragma("unroll")                                                           \
        for (int mi = 4; mi < 8; ++mi)                                              \
            af[mi] = *reinterpret_cast<const short8*>(&alp[ao[mi]]);                \
        __builtin_amdgcn_s_barrier();                                               \
        __builtin_amdgcn_s_setprio(1);                                              \
        _Pragma("unroll")                                                           \
        for (int mi = 4; mi < 8; ++mi)                                              \
            _Pragma("unroll")                                                       \
            for (int ni = 0; ni < 4; ++ni)                                          \
                acc[mi][ni] = __builtin_amdgcn_mfma_f32_16x16x32_bf16(              \
                    af[mi], bf[ni], acc[mi][ni], 0, 0, 0);                          \
        __builtin_amdgcn_s_setprio(0);                                              \
        VMW;                                                                        \
        __builtin_amdgcn_s_barrier();                                               \
    }

__global__ __launch_bounds__(512, 2) void conv_gemm_kernel(
        const unsigned short* __restrict__ wb,
        const unsigned short* __restrict__ xt,
        const float* __restrict__ bias,
        float* __restrict__ out) {
    __shared__ unsigned short a_lds[4][8192];   // 4 half-slots x 256 rows x 32 k
    __shared__ unsigned short b_lds[4][8192];

    int bid = blockIdx.x;
    int swz = (bid & 7) * 64 + (bid >> 3);
    int o0  = (swz & 1) * 256;
    int t0  = ((swz >> 1) & 15) * 256;
    int b   = swz >> 5;

    int tid  = threadIdx.x;
    int lane = tid & 63;
    int wid  = tid >> 6;       // 0..7
    int wm   = wid >> 2;       // 0..1 (m)
    int wn   = wid & 3;        // 0..3 (n)
    int lr   = lane & 15;
    int lg   = lane >> 4;

    int ao[8], bo[4];
#pragma unroll
    for (int mi = 0; mi < 8; ++mi) {
        int row = wm * 128 + mi * 16 + lr;
        ao[mi] = row * 32 + ((lg ^ ((row >> 1) & 3)) << 3);
    }
#pragma unroll
    for (int ni = 0; ni < 4; ++ni) {
        int row = wn * 64 + ni * 16 + lr;
        bo[ni] = row * 32 + ((lg ^ ((row >> 1) & 3)) << 3);
    }

    f32x4 acc[8][4];
#pragma unroll
    for (int mi = 0; mi < 8; ++mi)
#pragma unroll
        for (int ni = 0; ni < 4; ++ni)
            acc[mi][ni] = (f32x4)0.0f;

    int c8 = (lane & 3) ^ ((lane >> 3) & 3);
    const unsigned short* agl =
        wb + (size_t)(o0 + wid * 32 + (lane >> 2)) * C_ + c8 * 8;
    const unsigned short* bgl =
        xt + ((size_t)b * TP + 16 + t0 + wid * 32 + (lane >> 2)) * C_ + c8 * 8;

    // ---- prologue: stage halves 0,1,2 (all tap n=0)
#pragma unroll
    for (int h = 0; h < 3; ++h) {
        size_t off = (size_t)(((h >> 1) << 6) + ((h & 1) << 5));
        unsigned short* ad = &a_lds[h][wid * 1024];
        unsigned short* bd = &b_lds[h][wid * 1024];
        const unsigned short* as = agl + off;
        const unsigned short* bs = bgl + 2 * C_ + off;
        gload_lds16(as, ad);
        gload_lds16(as + 16 * C_, ad + 512);
        gload_lds16(bs, bd);
        gload_lds16(bs + 16 * C_, bd + 512);
    }
    VM8;
    __builtin_amdgcn_s_barrier();

#pragma unroll 1
    for (int hg = 0; hg < 19; ++hg) {
        int H = hg * 4;
        HALF_BODY(0, H + 0, 1, VM8);
        HALF_BODY(1, H + 1, 1, VM8);
        HALF_BODY(2, H + 2, 1, VM8);
        HALF_BODY(3, H + 3, 1, VM8);
    }
    HALF_BODY(0, 76, 1, VM8);
    HALF_BODY(1, 77, 0, VM4);
    HALF_BODY(2, 78, 0, VM0);
    HALF_BODY(3, 79, 0, VMNONE);

    // ---- epilogue: C/D layout col=lane&15, row=(lane>>4)*4+reg
#pragma unroll
    for (int mi = 0; mi < 8; ++mi) {
#pragma unroll
        for (int ni = 0; ni < 4; ++ni) {
            int orow = o0 + wm * 128 + mi * 16 + lg * 4;
            int tcol = t0 + wn * 64 + ni * 16 + lr;
#pragma unroll
            for (int r = 0; r < 4; ++r) {
                out[((size_t)b * O_ + orow + r) * T_ + tcol] =
                    acc[mi][ni][r] + bias[orow + r];
            }
        }
    }
}

extern "C" void kernel_launch(void* const* d_in, const int* in_sizes, int n_in,
                              void* d_out, int out_size, void* d_ws, size_t ws_size,
                              hipStream_t stream) {
    const float* x    = (const float*)d_in[0];
    const float* w    = (const float*)d_in[1];
    const float* bias = (const float*)d_in[2];
    float* out        = (float*)d_out;

    unsigned short* wb  = (unsigned short*)d_ws;            // 2.62 MB
    unsigned short* xtp = wb + (size_t)KT * OC;             // 16*4128*512 bf16 = 67.7 MB

    prep_kernel<<<6144, 256, 0, stream>>>(w, wb, xtp);
    xtrans_kernel<<<dim3(T_ / 64, C_ / 64, B_), 256, 0, stream>>>(x, xtp);
    conv_gemm_kernel<<<512, 512, 0, stream>>>(wb, xtp, bias, out);
}

// Round 11
// 190.400 us; speedup vs baseline: 1.1544x; 1.1544x over previous
//
#include <hip/hip_runtime.h>
#include <hip/hip_bf16.h>

typedef __attribute__((ext_vector_type(8))) short short8;
typedef __attribute__((ext_vector_type(4))) float f32x4;

#define B_   16
#define O_   512
#define C_   512
#define T_   4096
#define TP   (T_ + 32)     // padded t extent: 16 zero rows each side
#define KT   5
#define BM   128
#define BN   512
#define BK   32
#define NCHUNK (C_/BK)
#define AFR  40            // A fragments: 5 taps x 8 rowblocks, 1024B each
#define BGR  33            // B row-groups: 33 x 16 rows x 64B

__device__ __forceinline__ void gload_lds16(const void* g, void* l) {
    __builtin_amdgcn_global_load_lds(
        (const __attribute__((address_space(1))) unsigned int*)g,
        (__attribute__((address_space(3))) unsigned int*)l, 16, 0, 0);
}

#define VMW_(N) asm volatile("s_waitcnt vmcnt(" #N ")" ::: "memory")
#define VMW(N)  VMW_(N)

// ---------------- fused prep: wrepack (blocks 0..5119) + padzero (5120..6143) ----
__global__ void prep_kernel(const float* __restrict__ w,
                            unsigned short* __restrict__ wb,
                            unsigned short* __restrict__ xt) {
    int bid = blockIdx.x;
    if (bid < 5120) {
        int e   = bid * 256 + threadIdx.x;
        int n   = e / (O_ * C_);
        int rem = e % (O_ * C_);
        int o   = rem / C_;
        int c   = rem % C_;
        float v = w[((size_t)o * C_ + c) * KT + n];
        __hip_bfloat16 h = __float2bfloat16(v);
        wb[e] = *reinterpret_cast<unsigned short*>(&h);
    } else {
        int i = (bid - 5120) * 256 + threadIdx.x;
        int b = i / (32 * C_);
        int r = (i / C_) % 32;
        int c = i % C_;
        int tp = (r < 16) ? r : (T_ + r);
        xt[((size_t)b * TP + tp) * C_ + c] = 0;
    }
}

// ---------------- x transpose: x[b][c][t] f32 -> xT[b][16+t][c] bf16 ----------------
__global__ void xtrans_kernel(const float* __restrict__ x, unsigned short* __restrict__ xt) {
    __shared__ float tile[64][65];
    int b  = blockIdx.z;
    int c0 = blockIdx.y * 64;
    int t0 = blockIdx.x * 64;
    const float* xb = x + ((size_t)b * C_ + c0) * T_ + t0;
#pragma unroll
    for (int p = 0; p < 4; ++p) {
        int idx = p * 256 + threadIdx.x;
        int cl = idx >> 4;
        int tj = (idx & 15) << 2;
        float4 v = *reinterpret_cast<const float4*>(xb + (size_t)cl * T_ + tj);
        tile[cl][tj + 0] = v.x;
        tile[cl][tj + 1] = v.y;
        tile[cl][tj + 2] = v.z;
        tile[cl][tj + 3] = v.w;
    }
    __syncthreads();
    unsigned short* xtb = xt + ((size_t)b * TP + 16 + t0) * C_ + c0;
#pragma unroll
    for (int p = 0; p < 2; ++p) {
        int g  = p * 256 + threadIdx.x;
        int tl = g >> 3;
        int cj = (g & 7) << 3;
        unsigned short tmp[8];
#pragma unroll
        for (int i = 0; i < 8; ++i) {
            __hip_bfloat16 h = __float2bfloat16(tile[cj + i][tl]);
            tmp[i] = *reinterpret_cast<unsigned short*>(&h);
        }
        *reinterpret_cast<short8*>(xtb + (size_t)tl * C_ + cj) =
            *reinterpret_cast<const short8*>(tmp);
    }
}

// ---------------- conv-as-GEMM, phased pipeline, counted vmcnt (T4) ----------------
// Block tile 128(o) x 512(t), BK=32, 8 waves, wave tile 128x64 (1M x 8N).
// A: fragment-major LDS (zero-conflict). B: row-major [528][32], XOR slot swizzle.
// Per-wave issue order per chunk (staging chunk+1): [B x5, A0, A1, A2, A3, A4]
// (uniform 10/wave; waves 1-7 issue one benign duplicate B). Phase p of chunk k
// needs chunk k-1's first 6+p loads landed -> allowed outstanding =
// (4-p) leftover + (6+p) new = vmcnt(10) constant, never 0 in the main loop.
// Phase = {issue; vmcnt(10); barrier; ds_read; MFMA}. Chunk end: plain barrier.
#define PHASE(n, VMN, PF)                                                           \
    {                                                                               \
        if (PF) {                                                                   \
            if ((n) == 0) {                                                         \
                _Pragma("unroll")                                                   \
                for (int k = 0; k < 4; ++k)                                         \
                    gload_lds16(bg + (size_t)((wid + 8 * k) * 16) * C_ + c1,        \
                                &b_lds[nxt][(wid + 8 * k) * 512]);                  \
                gload_lds16(bg + (size_t)(je * 16) * C_ + c1,                       \
                            &b_lds[nxt][je * 512]);                                 \
            }                                                                       \
            gload_lds16(ag + (size_t)((n) * O_ + wid * 16) * C_ + c1,               \
                        &a_lds[nxt][((n) * 8 + wid) * 512]);                        \
        }                                                                           \
        VMW(VMN);                                                                   \
        __builtin_amdgcn_s_barrier();                                               \
        short8 af[8], bf[4];                                                        \
        _Pragma("unroll")                                                           \
        for (int mi = 0; mi < 8; ++mi)                                              \
            af[mi] = *reinterpret_cast<const short8*>(                              \
                &a_lds[cur][((n) * 8 + mi) * 512 + lane * 8]);                      \
        _Pragma("unroll")                                                           \
        for (int ni = 0; ni < 4; ++ni)                                              \
            bf[ni] = *reinterpret_cast<const short8*>(&b_lds[cur][bo[(n)][ni]]);    \
        __builtin_amdgcn_s_setprio(1);                                              \
        _Pragma("unroll")                                                           \
        for (int mi = 0; mi < 8; ++mi)                                              \
            _Pragma("unroll")                                                       \
            for (int ni = 0; ni < 4; ++ni)                                          \
                acc[mi][ni] = __builtin_amdgcn_mfma_f32_16x16x32_bf16(              \
                    af[mi], bf[ni], acc[mi][ni], 0, 0, 0);                          \
        __builtin_amdgcn_s_setprio(0);                                              \
    }

__global__ __launch_bounds__(512, 2) void conv_gemm_kernel(
        const unsigned short* __restrict__ wb,
        const unsigned short* __restrict__ xt,
        const float* __restrict__ bias,
        float* __restrict__ out) {
    __shared__ unsigned short a_lds[2][AFR * 512];   // 2 x 40960 B
    __shared__ unsigned short b_lds[2][BGR * 512];   // 2 x 33792 B

    // XCD-aware bijective swizzle (512 blocks): o-tile innermost.
    int bid = blockIdx.x;
    int swz = (bid & 7) * 64 + (bid >> 3);
    int o0  = (swz & 3) * BM;
    int t0  = ((swz >> 2) & 7) * BN;
    int b   = swz >> 5;

    int tid  = threadIdx.x;
    int lane = tid & 63;
    int wid  = tid >> 6;       // 0..7 = wave n-position
    int lr   = lane & 15;
    int lg   = lane >> 4;
    int je   = (wid == 0) ? 32 : (23 + wid);   // 5th B group (dup for wid>0)

    // chunk-invariant B read offsets (ushort units)
    int bo[KT][4];
#pragma unroll
    for (int n = 0; n < KT; ++n)
#pragma unroll
        for (int ni = 0; ni < 4; ++ni) {
            int row = wid * 64 + ni * 16 + lr + 4 - n;
            bo[n][ni] = row * 32 + ((lg ^ ((row >> 1) & 3)) << 3);
        }

    f32x4 acc[8][4];
#pragma unroll
    for (int mi = 0; mi < 8; ++mi)
#pragma unroll
        for (int ni = 0; ni < 4; ++ni)
            acc[mi][ni] = (f32x4)0.0f;

    // per-lane global staging bases
    const unsigned short* ag = wb + (size_t)(o0 + lr) * C_ + lg * 8;
    int c8 = (lane & 3) ^ ((lane >> 3) & 3);
    const unsigned short* bg = xt + ((size_t)b * TP + (t0 + 14 + (lane >> 2))) * C_ + c8 * 8;

    // ---- prologue: issue chunk 0's batch in canonical order [B x5, A0..A4]
#pragma unroll
    for (int k = 0; k < 4; ++k)
        gload_lds16(bg + (size_t)((wid + 8 * k) * 16) * C_, &b_lds[0][(wid + 8 * k) * 512]);
    gload_lds16(bg + (size_t)(je * 16) * C_, &b_lds[0][je * 512]);
#pragma unroll
    for (int n = 0; n < KT; ++n)
        gload_lds16(ag + (size_t)(n * O_ + wid * 16) * C_, &a_lds[0][(n * 8 + wid) * 512]);
    // no wait here: chunk-0 phase-0's vmcnt(10) covers the prologue batch.

    for (int chunk = 0; chunk < NCHUNK - 1; ++chunk) {
        int cur = chunk & 1;
        int nxt = cur ^ 1;
        int c1  = (chunk + 1) * BK;
        PHASE(0, 10, 1)
        PHASE(1, 10, 1)
        PHASE(2, 10, 1)
        PHASE(3, 10, 1)
        PHASE(4, 10, 1)
        __builtin_amdgcn_s_barrier();   // WAR: all reads of cur done before next writes
    }
    {   // ---- last chunk: drain 4 -> 0, no issues
        int cur = (NCHUNK - 1) & 1;
        int nxt = cur ^ 1;
        int c1  = 0;
        (void)nxt; (void)c1;
        PHASE(0, 4, 0)
        PHASE(1, 3, 0)
        PHASE(2, 2, 0)
        PHASE(3, 1, 0)
        PHASE(4, 0, 0)
    }

    // ---- epilogue: C/D layout col=lane&15, row=(lane>>4)*4+reg
#pragma unroll
    for (int mi = 0; mi < 8; ++mi) {
#pragma unroll
        for (int ni = 0; ni < 4; ++ni) {
            int orow = o0 + mi * 16 + lg * 4;
            int tcol = t0 + wid * 64 + ni * 16 + lr;
#pragma unroll
            for (int r = 0; r < 4; ++r) {
                out[((size_t)b * O_ + orow + r) * T_ + tcol] =
                    acc[mi][ni][r] + bias[orow + r];
            }
        }
    }
}

extern "C" void kernel_launch(void* const* d_in, const int* in_sizes, int n_in,
                              void* d_out, int out_size, void* d_ws, size_t ws_size,
                              hipStream_t stream) {
    const float* x    = (const float*)d_in[0];
    const float* w    = (const float*)d_in[1];
    const float* bias = (const float*)d_in[2];
    float* out        = (float*)d_out;

    unsigned short* wb  = (unsigned short*)d_ws;            // 2.62 MB
    unsigned short* xtp = wb + (size_t)KT * O_ * C_;        // 16*4128*512 bf16 = 67.7 MB

    prep_kernel<<<6144, 256, 0, stream>>>(w, wb, xtp);
    xtrans_kernel<<<dim3(T_ / 64, C_ / 64, B_), 256, 0, stream>>>(x, xtp);
    conv_gemm_kernel<<<512, 512, 0, stream>>>(wb, xtp, bias, out);
}